// Round 10
// baseline (1195.539 us; speedup 1.0000x reference)
//
#include <hip/hip_runtime.h>
#include <hip/hip_bf16.h>
#include <stdint.h>

// Int8Linear: y[m,n] = scale[n] * sum_k x[m,k]*w[n,k] + bias[n]
// Device dtypes: x fp32 [8192,4096]; w int32 [11008,4096] (|v|<=127);
// scale/bias fp32 [11008]; out fp32 [8192,11008].
// Round 10: LDS-pipe offload. r4-r9 all measured tile time = MFMA-pipe +
// LDS-pipe SUM (~4880 cyc) regardless of schedule/occupancy. Fix: B(W)
// fragments load DIRECT global->register (per-lane gather, 2x dup absorbed
// by L2/LLC; no barriers, prefetched 1 tile ahead, compiler-scheduled).
// A(X) stays LDS-staged with the r7/r8-validated conflict-free XOR swizzle.
// LDS 64 KiB (A dbuf only). 256x256 tile, BK=64, 8 waves, 1 barrier/tile.

#define K_DIM 4096
#define N_DIM 11008
#define M_DIM 8192

typedef __attribute__((ext_vector_type(8))) __bf16 bf16x8;
typedef __attribute__((ext_vector_type(4))) float f32x4;
typedef __attribute__((ext_vector_type(4))) int i32x4;

#define SB0 __builtin_amdgcn_sched_barrier(0)

__device__ __forceinline__ void gload_lds16(const void* g, void* l) {
  __builtin_amdgcn_global_load_lds(
      (const __attribute__((address_space(1))) void*)g,
      (__attribute__((address_space(3))) void*)l, 16, 0, 0);
}

// ---------------- prepass conversions (validated round 3) ----------------

__global__ void __launch_bounds__(256) wconv_kernel(const int* __restrict__ w,
                                                    __bf16* __restrict__ o,
                                                    int n8) {
  int i = blockIdx.x * 256 + threadIdx.x;
  if (i >= n8) return;
  const i32x4* src = (const i32x4*)w;
  i32x4 v0 = src[2 * i];
  i32x4 v1 = src[2 * i + 1];
  bf16x8 r;
#pragma unroll
  for (int j = 0; j < 4; ++j) {
    r[j]     = (__bf16)(float)v0[j];
    r[j + 4] = (__bf16)(float)v1[j];
  }
  *((bf16x8*)o + i) = r;
}

__global__ void __launch_bounds__(256) xconv_kernel(const float* __restrict__ x,
                                                    __bf16* __restrict__ o,
                                                    int n8) {
  int i = blockIdx.x * 256 + threadIdx.x;
  if (i >= n8) return;
  const f32x4* src = (const f32x4*)x;
  f32x4 v0 = src[2 * i];
  f32x4 v1 = src[2 * i + 1];
  bf16x8 r;
#pragma unroll
  for (int j = 0; j < 4; ++j) {
    r[j]     = (__bf16)v0[j];
    r[j + 4] = (__bf16)v1[j];
  }
  *((bf16x8*)o + i) = r;
}

// ---------------- 256x256 BK=64 GEMM, A-in-LDS / B-direct ----------------

#define BM 256
#define BN 256
#define BK 64
#define KT (K_DIM / BK)  /* 64 */
#define MT (M_DIM / BM)  /* 32 */
#define NT (N_DIM / BN)  /* 43 */
#define NBLK (MT * NT)   /* 1376 = 8*172 */
#define ATILE 16384      /* elems: A tile 256x64 */

__global__ void __launch_bounds__(512, 2) gemm256_kernel(
    const __bf16* __restrict__ Xb, const __bf16* __restrict__ Wb,
    const float* __restrict__ scale, const float* __restrict__ bias,
    float* __restrict__ out) {
  __shared__ __align__(16) __bf16 lds[2 * ATILE];  // 64 KiB (A dbuf only)

  const int tid = threadIdx.x;
  const int lane = tid & 63;
  const int wv = tid >> 6;  // 0..7
  const int wr = wv >> 2;   // 0..1 (M half: 128 rows)
  const int wc = wv & 3;    // 0..3 (N quarter: 64 cols)

  // T1: bijective XCD swizzle (1376 = 8*172)
  const int lid = blockIdx.x;
  const int swz = (lid & 7) * (NBLK / 8) + (lid >> 3);
  const int tm = swz / NT;
  const int tn = swz - tm * NT;
  const size_t m0 = (size_t)tm * BM;
  const size_t n0 = (size_t)tn * BN;

  // ---- A staging (r7/r8-validated): one call = 64 rows x 128B = 8 KB.
  // local row = tid>>3, 16B-slot = tid&7; LDS[row][s] holds global k-chunk
  // s ^ (row&7) -> inverse-swizzled per-lane global source, wave-uniform
  // LDS base (HW writes lane i at base + i*16B).
  const int srow = tid >> 3;  // 0..63
  const int gchunk = (tid & 7) ^ (srow & 7);
  const size_t gOff = (size_t)srow * K_DIM + gchunk * 8;
  const int ldsWv = wv * 512;  // wave-uniform elem offset within a call
  const __bf16* GA = Xb + m0 * K_DIM;

#define STGA(LP, R0, TS)                                             \
  gload_lds16(GA + (size_t)(R0) * K_DIM + (size_t)(TS) * BK + gOff,  \
              &lds[(LP) * ATILE + (R0) * 64 + ldsWv])

  // ---- A fragment reads (swizzled): slot = (ks*4+kg) ^ (fr&7) ----
  const int fr = lane & 15;
  const int kg = lane >> 4;
  const int sw = fr & 7;
  const int aBase = (wr * 128 + fr) * 64;
  const int s0 = ((0 * 4 + kg) ^ sw) * 8;
  const int s1 = ((1 * 4 + kg) ^ sw) * 8;

#define RDA(LP, RF, KS) \
  (*(const bf16x8*)&lds[(LP)*ATILE + aBase + (RF)*1024 + ((KS) ? s1 : s0)])

  // ---- B direct global->register fragment loads.
  // frag(nf,ks) row = n0 + wc*64 + nf*16 + fr ; k = t*64 + ks*32 + kg*8
  // (same mapping the r7 LDS path delivered, verified by r7 pass).
  const __bf16* gBf = Wb + (n0 + (size_t)wc * 64 + fr) * K_DIM + kg * 8;

#define LDB(NF, KS, T) \
  (*(const bf16x8*)(gBf + (size_t)(NF) * 16 * K_DIM + (size_t)(T) * BK + (KS) * 32))

  f32x4 acc[8][4];
#pragma unroll
  for (int m = 0; m < 8; ++m)
#pragma unroll
    for (int n = 0; n < 4; ++n) acc[m][n] = (f32x4){0.f, 0.f, 0.f, 0.f};

  bf16x8 bX[8], bY[8];

  // ---- prologue: stage A(0); load B(0) frags; drain; barrier ----
  STGA(0, 0, 0);
  STGA(0, 64, 0);
  STGA(0, 128, 0);
  STGA(0, 192, 0);
#pragma unroll
  for (int nf = 0; nf < 4; ++nf) {
    bX[nf * 2] = LDB(nf, 0, 0);
    bX[nf * 2 + 1] = LDB(nf, 1, 0);
  }
  asm volatile("s_waitcnt vmcnt(0)" ::: "memory");
  SB0;
  __builtin_amdgcn_s_barrier();

  // tile body: prefetch B(T+1)+stage A(T+1), compute T, 1 barrier.
#define TILE_BODY(BCUR, BNXT, T)                                          \
  do {                                                                    \
    const int p = (T) & 1;                                                \
    const int np = p ^ 1;                                                 \
    if ((T) + 1 < KT) {                                                   \
      _Pragma("unroll") for (int nf = 0; nf < 4; ++nf) {                  \
        BNXT[nf * 2] = LDB(nf, 0, (T) + 1);                               \
        BNXT[nf * 2 + 1] = LDB(nf, 1, (T) + 1);                           \
      }                                                                   \
      STGA(np, 0, (T) + 1);                                               \
      STGA(np, 64, (T) + 1);                                              \
      STGA(np, 128, (T) + 1);                                             \
      STGA(np, 192, (T) + 1);                                             \
    }                                                                     \
    SB0;                                                                  \
    _Pragma("unroll") for (int mf = 0; mf < 8; ++mf) {                    \
      bf16x8 a0 = RDA(p, mf, 0);                                          \
      bf16x8 a1 = RDA(p, mf, 1);                                          \
      _Pragma("unroll") for (int nf = 0; nf < 4; ++nf) {                  \
        acc[mf][nf] = __builtin_amdgcn_mfma_f32_16x16x32_bf16(            \
            a0, BCUR[nf * 2], acc[mf][nf], 0, 0, 0);                      \
        acc[mf][nf] = __builtin_amdgcn_mfma_f32_16x16x32_bf16(            \
            a1, BCUR[nf * 2 + 1], acc[mf][nf], 0, 0, 0);                  \
      }                                                                   \
    }                                                                     \
    asm volatile("s_waitcnt lgkmcnt(0)" ::: "memory");                    \
    asm volatile("s_waitcnt vmcnt(0)" ::: "memory");                      \
    __builtin_amdgcn_s_barrier();                                         \
  } while (0)

  for (int t = 0; t < KT; t += 2) {
    TILE_BODY(bX, bY, t);
    TILE_BODY(bY, bX, t + 1);
  }
#undef TILE_BODY

  // ---- epilogue: C/D layout col=lane&15, row=(lane>>4)*4+reg ----
  const int cc = lane & 15;
  const int rr = (lane >> 4) * 4;
#pragma unroll
  for (int nf = 0; nf < 4; ++nf) {
    const int col = (int)n0 + wc * 64 + nf * 16 + cc;
    const float sc = scale[col];
    const float bi = bias[col];
#pragma unroll
    for (int mf = 0; mf < 8; ++mf) {
      const size_t rowb = m0 + wr * 128 + mf * 16 + rr;
#pragma unroll
      for (int r = 0; r < 4; ++r) {
        out[(rowb + r) * N_DIM + col] = acc[mf][nf][r] * sc + bi;
      }
    }
  }
#undef STGA
#undef RDA
#undef LDB
}

// ---------------- fallback 128x128 kernel (round-3 validated) ----------------

#define FBM 128
#define FBN 128
#define FBK 32
#define FNT (N_DIM / FBN) /* 86 */
#define FMT (M_DIM / FBM) /* 64 */

__device__ __forceinline__ bf16x8 cvt8f(f32x4 a, f32x4 b) {
  bf16x8 h;
#pragma unroll
  for (int j = 0; j < 4; ++j) {
    h[j] = (__bf16)a[j];
    h[j + 4] = (__bf16)b[j];
  }
  return h;
}

__device__ __forceinline__ bf16x8 cvt8i(i32x4 a, i32x4 b) {
  bf16x8 h;
#pragma unroll
  for (int j = 0; j < 4; ++j) {
    h[j] = (__bf16)(float)a[j];
    h[j + 4] = (__bf16)(float)b[j];
  }
  return h;
}

template <int MODE>  // 1: W preconv; 2: no workspace
__global__ void __launch_bounds__(256, 2) gemm_fb_kernel(
    const float* __restrict__ X, const __bf16* __restrict__ Wb,
    const int* __restrict__ Wq, const float* __restrict__ scale,
    const float* __restrict__ bias, float* __restrict__ out) {
  __shared__ __align__(16) __bf16 As[FBM * FBK];
  __shared__ __align__(16) __bf16 Bs[FBN * FBK];

  const int tid = threadIdx.x;
  const int lane = tid & 63;
  const int wv = tid >> 6;

  const int lid = blockIdx.x;
  const int swz = (lid & 7) * ((FMT * FNT) >> 3) + (lid >> 3);
  const int tm = swz / FNT;
  const int tn = swz - tm * FNT;
  const int m0 = tm * FBM;
  const int n0 = tn * FBN;

  const int e0 = wv * 512 + lane * 8;
  const int e1 = e0 + 2048;
  const int r0 = e0 >> 5, c0 = e0 & 31;
  const int r1 = e1 >> 5, c1 = e1 & 31;

  f32x4 acc[4][4];
#pragma unroll
  for (int m = 0; m < 4; ++m)
#pragma unroll
    for (int n = 0; n < 4; ++n) acc[m][n] = (f32x4){0.f, 0.f, 0.f, 0.f};

  const int wm = (wv >> 1) * 64;
  const int wn = (wv & 1) * 64;
  const int fr = lane & 15;
  const int kc = (lane >> 4) * 8;

  const float* srcAf0 = X + (size_t)(m0 + r0) * K_DIM + c0;
  const float* srcAf1 = X + (size_t)(m0 + r1) * K_DIM + c1;
  const __bf16* srcBb0 = Wb + (size_t)(n0 + r0) * K_DIM + c0;
  const __bf16* srcBb1 = Wb + (size_t)(n0 + r1) * K_DIM + c1;
  const int* srcQ0 = Wq + (size_t)(n0 + r0) * K_DIM + c0;
  const int* srcQ1 = Wq + (size_t)(n0 + r1) * K_DIM + c1;

  for (int k0 = 0; k0 < K_DIM; k0 += FBK) {
    f32x4 a0 = *(const f32x4*)(srcAf0 + k0);
    f32x4 a1 = *(const f32x4*)(srcAf0 + k0 + 4);
    f32x4 a2 = *(const f32x4*)(srcAf1 + k0);
    f32x4 a3 = *(const f32x4*)(srcAf1 + k0 + 4);
    if constexpr (MODE == 1) {
      gload_lds16(srcBb0 + k0, &Bs[e0]);
      gload_lds16(srcBb1 + k0, &Bs[e1]);
    } else {
      i32x4 q0 = *(const i32x4*)(srcQ0 + k0);
      i32x4 q1 = *(const i32x4*)(srcQ0 + k0 + 4);
      i32x4 q2 = *(const i32x4*)(srcQ1 + k0);
      i32x4 q3 = *(const i32x4*)(srcQ1 + k0 + 4);
      *(bf16x8*)&Bs[e0] = cvt8i(q0, q1);
      *(bf16x8*)&Bs[e1] = cvt8i(q2, q3);
    }
    *(bf16x8*)&As[e0] = cvt8f(a0, a1);
    *(bf16x8*)&As[e1] = cvt8f(a2, a3);
    __syncthreads();

    bf16x8 a[4], b[4];
#pragma unroll
    for (int m = 0; m < 4; ++m)
      a[m] = *(const bf16x8*)&As[(wm + m * 16 + fr) * FBK + kc];
#pragma unroll
    for (int n = 0; n < 4; ++n)
      b[n] = *(const bf16x8*)&Bs[(wn + n * 16 + fr) * FBK + kc];
#pragma unroll
    for (int m = 0; m < 4; ++m)
#pragma unroll
      for (int n = 0; n < 4; ++n)
        acc[m][n] = __builtin_amdgcn_mfma_f32_16x16x32_bf16(a[m], b[n],
                                                            acc[m][n], 0, 0, 0);
    __syncthreads();
  }

  const int cc = lane & 15;
  const int rr = (lane >> 4) * 4;
#pragma unroll
  for (int n = 0; n < 4; ++n) {
    const int col = n0 + wn + n * 16 + cc;
    const float sc = scale[col];
    const float bi = bias[col];
#pragma unroll
    for (int m = 0; m < 4; ++m) {
      const int rowb = m0 + wm + m * 16 + rr;
#pragma unroll
      for (int r = 0; r < 4; ++r) {
        out[(size_t)(rowb + r) * N_DIM + col] = acc[m][n][r] * sc + bi;
      }
    }
  }
}

// ---------------- launch ----------------

extern "C" void kernel_launch(void* const* d_in, const int* in_sizes, int n_in,
                              void* d_out, int out_size, void* d_ws, size_t ws_size,
                              hipStream_t stream) {
  const float* X = (const float*)d_in[0];
  const int* Wq = (const int*)d_in[1];
  const float* scale = (const float*)d_in[2];
  const float* bias = (const float*)d_in[3];
  float* out = (float*)d_out;

  const size_t wbytes = (size_t)N_DIM * K_DIM * sizeof(__bf16);  // 90,177,536
  const size_t xbytes = (size_t)M_DIM * K_DIM * sizeof(__bf16);  // 67,108,864
  const int n8w = (N_DIM * K_DIM) / 8;
  const int n8x = (M_DIM * K_DIM) / 8;

  if (ws_size >= wbytes + xbytes) {
    __bf16* Wb = (__bf16*)d_ws;
    __bf16* Xb = (__bf16*)((char*)d_ws + wbytes);
    wconv_kernel<<<dim3((n8w + 255) / 256), dim3(256), 0, stream>>>(Wq, Wb, n8w);
    xconv_kernel<<<dim3((n8x + 255) / 256), dim3(256), 0, stream>>>(X, Xb, n8x);
    gemm256_kernel<<<dim3(NBLK), dim3(512), 0, stream>>>(Xb, Wb, scale, bias, out);
  } else if (ws_size >= wbytes) {
    __bf16* Wb = (__bf16*)d_ws;
    wconv_kernel<<<dim3((n8w + 255) / 256), dim3(256), 0, stream>>>(Wq, Wb, n8w);
    gemm_fb_kernel<1><<<dim3(FMT * FNT), dim3(256), 0, stream>>>(
        X, Wb, Wq, scale, bias, out);
  } else {
    gemm_fb_kernel<2><<<dim3(FMT * FNT), dim3(256), 0, stream>>>(
        X, nullptr, Wq, scale, bias, out);
  }
}